// Round 1
// 102.740 us; speedup vs baseline: 1.0294x; 1.0294x over previous
//
#include <hip/hip_runtime.h>

#define BATCH 2
#define H 512
#define W 512
#define CS 21
#define CI 3
#define P 128                   // pixels per block (x)
#define R 4                     // output rows per block (vertical run)
#define TPB 256
#define GROWS (R + 2)           // 6 tap rows
#define GSL (P + 2)             // 130 guide slots incl. halo
#define GSZ (GROWS * GSL * CI)  // 2340 guide floats
#define PRE_ROWS 4              // it=0 tap rows prefetched before staging

typedef float f32x4 __attribute__((ext_vector_type(4)));

__device__ __forceinline__ void fma4(float4& a, const float4 v, const float w) {
    a.x = fmaf(v.x, w, a.x);
    a.y = fmaf(v.y, w, a.y);
    a.z = fmaf(v.z, w, a.z);
    a.w = fmaf(v.w, w, a.w);
}

// out is never re-read: nt store avoids L2 write-allocate evicting src halo.
__device__ __forceinline__ void nt_store4(float* p, const float4 v) {
    __builtin_nontemporal_store(*(const f32x4*)&v, (f32x4*)p);
}

// No src staging in LDS (R4/R5 barrier-serialization lesson). Each item owns
// a vertical run of 4 output rows for one (px, chunk). New this round:
//  - it=0 rows 0..3 prefetched into registers BEFORE guide staging, so src
//    streaming overlaps the stage+weight phases instead of starting cold.
//  - guide tile staged via global_load_lds (async, single vmcnt drain).
//  - nontemporal output stores.
__global__ __launch_bounds__(TPB, 4) void jbu_kernel(
    const float* __restrict__ src, const float* __restrict__ im,
    float* __restrict__ out)
{
    __shared__ float s_g[GSZ];                    // 9,360 B guide tile
    __shared__ __align__(16) float s_w[R * P * 12];  // 24,576 B weights

    const int t = threadIdx.x;

    // XCD swizzle: XCD (f&7) owns a contiguous 64-output-row band.
    const int f      = blockIdx.x;        // 0..1023
    const int xcd    = f & 7;
    const int g      = f >> 3;            // 0..127
    const int rowgrp = (xcd << 4) | (g & 15);   // 0..127
    const int rem    = g >> 4;            // 0..7
    const int x0     = (rem & 3) << 7;    // segment * 128
    const int b      = rem >> 2;
    const int y0     = rowgrp << 2;       // output rows y0..y0+3

    const size_t rs = (size_t)W * CS;
    const float* sb = src + (size_t)b * H * rs;
    const float* srow[GROWS];
    #pragma unroll
    for (int rr = 0; rr < GROWS; ++rr) {
        int v = y0 - 1 + rr;
        int tyr = (v < 0) ? 1 : ((v >= H) ? 2 * H - 2 - v : v);
        srow[rr] = sb + (size_t)tyr * rs + (size_t)x0 * CS;
    }

    // ---- it=0 tap prefetch (rows 0..PRE_ROWS-1) ----
    // 12 float4 (48 VGPR) live across both barriers; the barrier's vmcnt(0)
    // drain completes them while the guide tile is also in flight.
    const int px0   = t / 6;              // 0..42
    const int q0    = t - px0 * 6;
    const int coff0 = (q0 == 5) ? 17 : (q0 << 2);
    const int x_    = x0 + px0;
    const int xm_   = (x_ == 0)     ? 1     : x_ - 1;
    const int xp_   = (x_ == W - 1) ? W - 2 : x_ + 1;
    const int om0   = (xm_ - x0) * CS + coff0;   // may be negative: valid in-row
    const int oc0   = px0 * CS + coff0;
    const int op0   = (xp_ - x0) * CS + coff0;

    float4 v0[PRE_ROWS][3];
    #pragma unroll
    for (int rr = 0; rr < PRE_ROWS; ++rr) {
        v0[rr][0] = *(const float4*)(srow[rr] + om0);
        v0[rr][1] = *(const float4*)(srow[rr] + oc0);
        v0[rr][2] = *(const float4*)(srow[rr] + op0);
    }

    // ---- stage guide tile: async global->LDS ----
    // dest s_g+i is wave-uniform base + lane*4 (i = k*TPB + t), matching the
    // global_load_lds linear-destination requirement.
    const float* imb = im + (size_t)b * (H * W * CI);
    for (int i = t; i < GSZ; i += TPB) {
        int rr   = i / (GSL * CI);
        int remi = i - rr * (GSL * CI);
        int slot = remi / CI;
        int ch   = remi - slot * CI;
        int gx   = x0 + slot - 1;
        gx = (gx < 0) ? 1 : ((gx >= W) ? W - 2 : gx);
        int vv = y0 - 1 + rr;
        int tyr = (vv < 0) ? 1 : ((vv >= H) ? 2 * H - 2 - vv : vv);
        const float* gsrc = imb + ((size_t)tyr * W + gx) * CI + ch;
        __builtin_amdgcn_global_load_lds(
            (const __attribute__((address_space(1))) void*)gsrc,
            (__attribute__((address_space(3))) void*)(s_g + i), 4, 0, 0);
    }
    __syncthreads();

    // ---- weights: R*P = 512 sets, 2 per thread, normalized ----
    {
        const float w1k[9] = {0.36787944f, 0.60653066f, 0.36787944f,
                              0.60653066f, 1.0f,        0.60653066f,
                              0.36787944f, 0.60653066f, 0.36787944f};
        #pragma unroll
        for (int ii = 0; ii < (R * P) / TPB; ++ii) {
            int idx = ii * TPB + t;       // 0..511
            int r   = idx >> 7;           // 0..3   (idx / P)
            int px  = idx & (P - 1);
            int cb  = ((r + 1) * GSL + px + 1) * CI;
            float c0 = s_g[cb + 0], c1 = s_g[cb + 1], c2 = s_g[cb + 2];
            float wv[9];
            float den = 0.f;
            #pragma unroll
            for (int k = 0; k < 9; ++k) {
                int dy = k / 3, dx = k % 3;
                int ib = ((r + dy) * GSL + px + dx) * CI;
                float d0 = s_g[ib + 0] - c0;
                float d1 = s_g[ib + 1] - c1;
                float d2 = s_g[ib + 2] - c2;
                float w = __expf(-8.0f * (d0 * d0 + d1 * d1 + d2 * d2)) * w1k[k];
                wv[k] = w;
                den += w;
            }
            float inv = 1.0f / den;
            float* wd = &s_w[idx * 12];
            *(float4*)(wd + 0) = make_float4(wv[0] * inv, wv[1] * inv, wv[2] * inv, wv[3] * inv);
            *(float4*)(wd + 4) = make_float4(wv[4] * inv, wv[5] * inv, wv[6] * inv, wv[7] * inv);
            wd[8] = wv[8] * inv;
        }
    }
    __syncthreads();

    // ---- phase 2: vertical-run taps from global, weights from LDS ----
    float* ob = out + ((size_t)(b * H + y0)) * rs + (size_t)x0 * CS;

    // it = 0: prefetched rows + remaining two tap rows
    {
        float4 v[GROWS][3];
        #pragma unroll
        for (int rr = 0; rr < PRE_ROWS; ++rr) {
            v[rr][0] = v0[rr][0]; v[rr][1] = v0[rr][1]; v[rr][2] = v0[rr][2];
        }
        #pragma unroll
        for (int rr = PRE_ROWS; rr < GROWS; ++rr) {
            v[rr][0] = *(const float4*)(srow[rr] + om0);
            v[rr][1] = *(const float4*)(srow[rr] + oc0);
            v[rr][2] = *(const float4*)(srow[rr] + op0);
        }
        #pragma unroll
        for (int j = 0; j < R; ++j) {
            const float* wd = &s_w[(((j << 7) + px0)) * 12];
            float4 wA = *(const float4*)(wd + 0);
            float4 wB = *(const float4*)(wd + 4);
            float  w8 = wd[8];
            float4 acc = {0.f, 0.f, 0.f, 0.f};
            fma4(acc, v[j + 0][0], wA.x);
            fma4(acc, v[j + 0][1], wA.y);
            fma4(acc, v[j + 0][2], wA.z);
            fma4(acc, v[j + 1][0], wA.w);
            fma4(acc, v[j + 1][1], wB.x);
            fma4(acc, v[j + 1][2], wB.y);
            fma4(acc, v[j + 2][0], wB.z);
            fma4(acc, v[j + 2][1], wB.w);
            fma4(acc, v[j + 2][2], w8);
            nt_store4(ob + (size_t)j * rs + oc0, acc);
        }
    }

    // it = 1,2
    #pragma unroll
    for (int it = 1; it < (P * 6) / TPB; ++it) {
        int item = it * TPB + t;
        int px = item / 6;
        int q  = item - px * 6;
        int coff = (q == 5) ? 17 : (q << 2);
        int x  = x0 + px;
        int xm = (x == 0)     ? 1     : x - 1;
        int xp = (x == W - 1) ? W - 2 : x + 1;
        int om = (xm - x0) * CS + coff;
        int oc = px * CS + coff;
        int op = (xp - x0) * CS + coff;

        float4 v[GROWS][3];
        #pragma unroll
        for (int rr = 0; rr < GROWS; ++rr) {
            v[rr][0] = *(const float4*)(srow[rr] + om);
            v[rr][1] = *(const float4*)(srow[rr] + oc);
            v[rr][2] = *(const float4*)(srow[rr] + op);
        }

        #pragma unroll
        for (int j = 0; j < R; ++j) {
            const float* wd = &s_w[(((j << 7) + px)) * 12];
            float4 wA = *(const float4*)(wd + 0);
            float4 wB = *(const float4*)(wd + 4);
            float  w8 = wd[8];
            float4 acc = {0.f, 0.f, 0.f, 0.f};
            fma4(acc, v[j + 0][0], wA.x);
            fma4(acc, v[j + 0][1], wA.y);
            fma4(acc, v[j + 0][2], wA.z);
            fma4(acc, v[j + 1][0], wA.w);
            fma4(acc, v[j + 1][1], wB.x);
            fma4(acc, v[j + 1][2], wB.y);
            fma4(acc, v[j + 2][0], wB.z);
            fma4(acc, v[j + 2][1], wB.w);
            fma4(acc, v[j + 2][2], w8);
            nt_store4(ob + (size_t)j * rs + oc, acc);
        }
    }
}

extern "C" void kernel_launch(void* const* d_in, const int* in_sizes, int n_in,
                              void* d_out, int out_size, void* d_ws, size_t ws_size,
                              hipStream_t stream) {
    const float* src = (const float*)d_in[0];
    const float* im  = (const float*)d_in[1];
    float* out = (float*)d_out;
    dim3 grid((W / P) * (H / R) * BATCH, 1, 1);   // 1024 blocks = 4/CU
    jbu_kernel<<<grid, TPB, 0, stream>>>(src, im, out);
}

// Round 2
// 100.074 us; speedup vs baseline: 1.0568x; 1.0266x over previous
//
#include <hip/hip_runtime.h>

#define BATCH 2
#define H 512
#define W 512
#define CS 21
#define CI 3
#define P 128                   // pixels per block (x)
#define R 8                     // output rows per block (vertical run)
#define TPB 256
#define GROWS (R + 2)           // 10 tap rows
#define GSL (P + 2)             // 130 guide slots incl. halo
#define GSZ (GROWS * GSL * CI)  // 3900 guide floats

typedef float f32x4 __attribute__((ext_vector_type(4)));

__device__ __forceinline__ void fma4(float4& a, const float4 v, const float w) {
    a.x = fmaf(v.x, w, a.x);
    a.y = fmaf(v.y, w, a.y);
    a.z = fmaf(v.z, w, a.z);
    a.w = fmaf(v.w, w, a.w);
}

// out is never re-read: nt store avoids L2 write-allocate evicting src halo.
__device__ __forceinline__ void nt_store4(float* p, const float4 v) {
    __builtin_nontemporal_store(*(const f32x4*)&v, (f32x4*)p);
}

// Load the 3 x-taps of one src row into a float4[3].
#define LOAD3(dst, rr, om, oc, op)                              \
    (dst)[0] = *(const float4*)(srow[rr] + (om));               \
    (dst)[1] = *(const float4*)(srow[rr] + (oc));               \
    (dst)[2] = *(const float4*)(srow[rr] + (op));

// Row selector: rows 0..5 live in va[6][3], rows 6..9 in vb[4][3].
// All indices are compile-time after unroll (rule #20: no scratch).
#define VA_I(r) ((r) < 6 ? (r) : 5)
#define VB_I(r) ((r) < 6 ? 0 : (r) - 6)
#define VR(va, vb, r, k) ((r) < 6 ? (va)[VA_I(r)][(k)] : (vb)[VB_I(r)][(k)])

// 8-row vertical run: same fma ordering as the R=4 kernel (bit-identical).
#define COMPUTE8(va, vb, px, oc)                                             \
    {                                                                        \
        _Pragma("unroll")                                                    \
        for (int j = 0; j < R; ++j) {                                        \
            const float* wd = &s_w[((j << 7) + (px)) * 12];                  \
            float4 wA = *(const float4*)(wd + 0);                            \
            float4 wB = *(const float4*)(wd + 4);                            \
            float  w8 = wd[8];                                               \
            float4 acc = {0.f, 0.f, 0.f, 0.f};                               \
            fma4(acc, VR(va, vb, j + 0, 0), wA.x);                           \
            fma4(acc, VR(va, vb, j + 0, 1), wA.y);                           \
            fma4(acc, VR(va, vb, j + 0, 2), wA.z);                           \
            fma4(acc, VR(va, vb, j + 1, 0), wA.w);                           \
            fma4(acc, VR(va, vb, j + 1, 1), wB.x);                           \
            fma4(acc, VR(va, vb, j + 1, 2), wB.y);                           \
            fma4(acc, VR(va, vb, j + 2, 0), wB.z);                           \
            fma4(acc, VR(va, vb, j + 2, 1), wB.w);                           \
            fma4(acc, VR(va, vb, j + 2, 2), w8);                             \
            nt_store4(ob + (size_t)j * rs + (oc), acc);                      \
        }                                                                    \
    }

// R=8: 10 tap rows per 8 output rows cuts vertical src overfetch 1.5x->1.25x.
// 2 blocks/CU (64.8 KB LDS), 256-VGPR budget spent on prefetch depth:
//  - it0 full 6-row tap set before staging (18 f4)
//  - it1 rows 0..3 issued right after barrier 1, overlapping the weight phase
__global__ __launch_bounds__(TPB, 2) void jbu_kernel(
    const float* __restrict__ src, const float* __restrict__ im,
    float* __restrict__ out)
{
    __shared__ float s_g[GSZ];                       // 15,600 B guide tile
    __shared__ __align__(16) float s_w[R * P * 12];  // 49,152 B weights

    const int t = threadIdx.x;

    // XCD swizzle: XCD (f&7) owns a contiguous 64-output-row band.
    const int f      = blockIdx.x;        // 0..511
    const int xcd    = f & 7;
    const int g      = f >> 3;            // 0..63
    const int rowgrp = (xcd << 3) | (g & 7);    // 0..63
    const int rem    = g >> 3;            // 0..7
    const int x0     = (rem & 3) << 7;    // segment * 128
    const int b      = rem >> 2;
    const int y0     = rowgrp << 3;       // output rows y0..y0+7

    const size_t rs = (size_t)W * CS;
    const float* sb = src + (size_t)b * H * rs;
    const float* srow[GROWS];
    #pragma unroll
    for (int rr = 0; rr < GROWS; ++rr) {
        int v = y0 - 1 + rr;
        int tyr = (v < 0) ? 1 : ((v >= H) ? 2 * H - 2 - v : v);
        srow[rr] = sb + (size_t)tyr * rs + (size_t)x0 * CS;
    }

    // ---- it=0 addressing + full 6-row prefetch (rows 0..5) ----
    const int px0   = t / 6;              // 0..42
    const int q0    = t - px0 * 6;
    const int coff0 = (q0 == 5) ? 17 : (q0 << 2);
    const int x_    = x0 + px0;
    const int xm_   = (x_ == 0)     ? 1     : x_ - 1;
    const int xp_   = (x_ == W - 1) ? W - 2 : x_ + 1;
    const int om0   = (xm_ - x0) * CS + coff0;   // may be negative: valid in-row
    const int oc0   = px0 * CS + coff0;
    const int op0   = (xp_ - x0) * CS + coff0;

    float4 va0[6][3];
    #pragma unroll
    for (int rr = 0; rr < 6; ++rr) { LOAD3(va0[rr], rr, om0, oc0, op0) }

    // ---- stage guide tile: async global->LDS (linear dest = base + lane*4) ----
    const float* imb = im + (size_t)b * (H * W * CI);
    for (int i = t; i < GSZ; i += TPB) {
        int rr   = i / (GSL * CI);
        int remi = i - rr * (GSL * CI);
        int slot = remi / CI;
        int ch   = remi - slot * CI;
        int gx   = x0 + slot - 1;
        gx = (gx < 0) ? 1 : ((gx >= W) ? W - 2 : gx);
        int vv = y0 - 1 + rr;
        int tyr = (vv < 0) ? 1 : ((vv >= H) ? 2 * H - 2 - vv : vv);
        const float* gsrc = imb + ((size_t)tyr * W + gx) * CI + ch;
        __builtin_amdgcn_global_load_lds(
            (const __attribute__((address_space(1))) void*)gsrc,
            (__attribute__((address_space(3))) void*)(s_g + i), 4, 0, 0);
    }
    __syncthreads();

    // ---- it=1 addressing + rows 0..3 prefetch: streams during weight phase ----
    const int item1 = TPB + t;
    const int px1   = item1 / 6;          // 42..85
    const int q1    = item1 - px1 * 6;
    const int coff1 = (q1 == 5) ? 17 : (q1 << 2);
    const int x1    = x0 + px1;
    const int xm1   = (x1 == 0)     ? 1     : x1 - 1;
    const int xp1   = (x1 == W - 1) ? W - 2 : x1 + 1;
    const int om1   = (xm1 - x0) * CS + coff1;
    const int oc1   = px1 * CS + coff1;
    const int op1   = (xp1 - x0) * CS + coff1;

    float4 va1[6][3];
    #pragma unroll
    for (int rr = 0; rr < 4; ++rr) { LOAD3(va1[rr], rr, om1, oc1, op1) }

    // ---- weights: R*P = 1024 sets, 4 per thread, normalized ----
    {
        const float w1k[9] = {0.36787944f, 0.60653066f, 0.36787944f,
                              0.60653066f, 1.0f,        0.60653066f,
                              0.36787944f, 0.60653066f, 0.36787944f};
        #pragma unroll
        for (int ii = 0; ii < (R * P) / TPB; ++ii) {
            int idx = ii * TPB + t;       // 0..1023
            int r   = idx >> 7;           // 0..7   (idx / P)
            int px  = idx & (P - 1);
            int cb  = ((r + 1) * GSL + px + 1) * CI;
            float c0 = s_g[cb + 0], c1 = s_g[cb + 1], c2 = s_g[cb + 2];
            float wv[9];
            float den = 0.f;
            #pragma unroll
            for (int k = 0; k < 9; ++k) {
                int dy = k / 3, dx = k % 3;
                int ib = ((r + dy) * GSL + px + dx) * CI;
                float d0 = s_g[ib + 0] - c0;
                float d1 = s_g[ib + 1] - c1;
                float d2 = s_g[ib + 2] - c2;
                float w = __expf(-8.0f * (d0 * d0 + d1 * d1 + d2 * d2)) * w1k[k];
                wv[k] = w;
                den += w;
            }
            float inv = 1.0f / den;
            float* wd = &s_w[idx * 12];
            *(float4*)(wd + 0) = make_float4(wv[0] * inv, wv[1] * inv, wv[2] * inv, wv[3] * inv);
            *(float4*)(wd + 4) = make_float4(wv[4] * inv, wv[5] * inv, wv[6] * inv, wv[7] * inv);
            wd[8] = wv[8] * inv;
        }
    }
    __syncthreads();

    // ---- phase 2: 8-row vertical runs, taps from global, weights from LDS ----
    float* ob = out + ((size_t)(b * H + y0)) * rs + (size_t)x0 * CS;

    // it = 0: va0 ready; fetch rows 6..9 (hidden under j=0..3 fmas)
    {
        float4 vb0[4][3];
        #pragma unroll
        for (int rr = 0; rr < 4; ++rr) { LOAD3(vb0[rr], rr + 6, om0, oc0, op0) }
        COMPUTE8(va0, vb0, px0, oc0)
    }

    // it = 1: rows 0..3 prefetched; fetch rows 4..9
    {
        LOAD3(va1[4], 4, om1, oc1, op1)
        LOAD3(va1[5], 5, om1, oc1, op1)
        float4 vb1[4][3];
        #pragma unroll
        for (int rr = 0; rr < 4; ++rr) { LOAD3(vb1[rr], rr + 6, om1, oc1, op1) }
        COMPUTE8(va1, vb1, px1, oc1)
    }

    // it = 2: full load
    {
        const int item2 = 2 * TPB + t;
        const int px2   = item2 / 6;      // 85..127
        const int q2    = item2 - px2 * 6;
        const int coff2 = (q2 == 5) ? 17 : (q2 << 2);
        const int x2    = x0 + px2;
        const int xm2   = (x2 == 0)     ? 1     : x2 - 1;
        const int xp2   = (x2 == W - 1) ? W - 2 : x2 + 1;
        const int om2   = (xm2 - x0) * CS + coff2;
        const int oc2   = px2 * CS + coff2;
        const int op2   = (xp2 - x0) * CS + coff2;

        float4 va2[6][3];
        #pragma unroll
        for (int rr = 0; rr < 6; ++rr) { LOAD3(va2[rr], rr, om2, oc2, op2) }
        float4 vb2[4][3];
        #pragma unroll
        for (int rr = 0; rr < 4; ++rr) { LOAD3(vb2[rr], rr + 6, om2, oc2, op2) }
        COMPUTE8(va2, vb2, px2, oc2)
    }
}

extern "C" void kernel_launch(void* const* d_in, const int* in_sizes, int n_in,
                              void* d_out, int out_size, void* d_ws, size_t ws_size,
                              hipStream_t stream) {
    const float* src = (const float*)d_in[0];
    const float* im  = (const float*)d_in[1];
    float* out = (float*)d_out;
    dim3 grid((W / P) * (H / R) * BATCH, 1, 1);   // 512 blocks = 2/CU
    jbu_kernel<<<grid, TPB, 0, stream>>>(src, im, out);
}